// Round 2
// baseline (593.153 us; speedup 1.0000x reference)
//
#include <hip/hip_runtime.h>

typedef __attribute__((ext_vector_type(4))) float f32x4;
typedef __attribute__((ext_vector_type(8))) short bf16x8;
typedef unsigned long long u64;
typedef unsigned short u16;
typedef unsigned int u32;

// round-to-nearest-even f32 -> bf16 bits
static __device__ __forceinline__ u16 f2bf(float f) {
    u32 u = __float_as_uint(f);
    u += 0x7fffu + ((u >> 16) & 1u);
    return (u16)(u >> 16);
}

// ---------------- kernel 1: s[g][ic] = style[g] . mod_w[ic] + mod_b[ic] ----
__global__ void k_style(const float* __restrict__ style, const float* __restrict__ mod_w,
                        const float* __restrict__ mod_b, float* __restrict__ s_ws) {
    int t = blockIdx.x * 256 + threadIdx.x;     // 0..2047
    int g = t >> 9, ic = t & 511;
    const f32x4* st = (const f32x4*)(style + (g << 9));
    const f32x4* mw = (const f32x4*)(mod_w + (ic << 9));
    float acc = 0.f;
#pragma unroll 4
    for (int d = 0; d < 128; ++d) {
        f32x4 a = st[d], b = mw[d];
        acc += a[0]*b[0] + a[1]*b[1] + a[2]*b[2] + a[3]*b[3];
    }
    s_ws[t] = acc + mod_b[ic];
}

// ---------------- kernel 2: Wmod bf16, fragment-lane order ----------------
// Layout: [g(4)][ocb(4)][wr(2)][ch(8)][tap(9)][frag(8)][lane(64)][e(8)]
// frag = kk*4+m ; lane gives (l15->oc, l4->ic8-block)
// oc = ocb*128 + wr*64 + m*16 + l15 ; ic = ch*64 + kk*32 + l4*8 + e
__global__ void k_wmod(const float* __restrict__ weight, const float* __restrict__ demod,
                       const float* __restrict__ s_ws, short* __restrict__ wmod) {
    int t = blockIdx.x * 256 + threadIdx.x;     // [0, 2359296)
    int lane = t & 63;
    int r = t >> 6;
    int frag = r & 7; r >>= 3;
    int tap = r % 9; r /= 9;
    int ch = r & 7; r >>= 3;
    int wr = r & 1; r >>= 1;
    int ocb = r & 3; int g = r >> 2;
    int kk = frag >> 2, m = frag & 3;
    int oc  = ocb*128 + wr*64 + m*16 + (lane & 15);
    int ic0 = ch*64 + kk*32 + (lane >> 4)*8;
    const float* wp = weight + (size_t)(oc*512 + ic0)*9 + tap;
    const float* sp = s_ws + (g << 9) + ic0;
    const float* dp = demod + ic0;
    bf16x8 pk;
#pragma unroll
    for (int e = 0; e < 8; ++e)
        pk[e] = (short)f2bf(wp[e*9] * (sp[e] * dp[e]));
    ((bf16x8*)wmod)[t] = pk;
}

// ---------------- kernel 3: main implicit-GEMM conv ------------------------
// Block: 128 oc x 256 px (4 rows), BK=64 ic, taps fully unrolled, 4 waves.
// W: global->register double-buffer (no LDS, no per-tap barriers).
// Xs[391 slots][72 shorts]: slot p = row*65 + 1 + x; shared zero pads between
// rows (x=-1 of row r == x=64 of row r-1 == slot r*65). Stride 72 -> 2-way
// bank access on ds_read_b128 (free), 16B aligned.
__global__ __launch_bounds__(256, 2) void k_conv(const float* __restrict__ x,
                                                 const short* __restrict__ wmod,
                                                 float* __restrict__ out) {
    __shared__ __align__(16) short Xs[391 * 72];   // 56304 B

    const int tid  = threadIdx.x;
    const int lane = tid & 63;
    const int wv   = tid >> 6;
    const int wr   = wv >> 1, wc = wv & 1;
    const int l15  = lane & 15;
    const int l4   = lane >> 4;
    const int ocb  = blockIdx.x & 3, rowb = blockIdx.x >> 2;
    const int g    = blockIdx.y, nb = blockIdx.z;
    const int y0   = rowb << 2;

    const float* xg   = x + (((size_t)(nb * 2048 + (g << 9))) << 12);
    const short* wg   = wmod + ((size_t)((g * 4 + ocb) * 2 + wr)) * 294912;
    float* outg = out + (((size_t)(nb * 2048 + (g << 9) + ocb * 128)) << 12) + (rowb << 8);

    bf16x8 a[2][8];
    // prologue: prefetch (ch=0, tap=0) A-frags
#pragma unroll
    for (int f = 0; f < 8; ++f)
        a[0][f] = *(const bf16x8*)&wg[f * 512 + lane * 8];

    // zero Xs once (pads + out-of-image halo rows stay 0 forever)
    for (int i = tid; i < (391 * 72) / 4; i += 256) ((u64*)Xs)[i] = 0ull;

    f32x4 acc[4][8];
#pragma unroll
    for (int m = 0; m < 4; ++m)
#pragma unroll
        for (int nn = 0; nn < 8; ++nn) acc[m][nn] = (f32x4){0.f, 0.f, 0.f, 0.f};

    const int q = tid & 15, icg4 = tid >> 4;

    for (int ch = 0; ch < 8; ++ch) {
        if (ch > 0) {   // prefetch this chunk's tap-0 A-frags; lands during staging
            const short* wn = wg + (size_t)ch * 9 * 4096;
#pragma unroll
            for (int f = 0; f < 8; ++f)
                a[0][f] = *(const bf16x8*)&wn[f * 512 + lane * 8];
        }
        __syncthreads();   // previous chunk's Xs reads complete

        // ---- stage X: fp32 -> bf16, transposed [slot p][ic] ----
#pragma unroll
        for (int r = 0; r < 6; ++r) {
            const int gy = y0 - 1 + r;
            if (gy >= 0 && gy <= 63) {
                const float* src = xg + (((size_t)((ch << 6) + (icg4 << 2))) << 12) + (gy << 6) + (q << 2);
                f32x4 v0 = *(const f32x4*)(src);
                f32x4 v1 = *(const f32x4*)(src + 4096);
                f32x4 v2 = *(const f32x4*)(src + 8192);
                f32x4 v3 = *(const f32x4*)(src + 12288);
#pragma unroll
                for (int c = 0; c < 4; ++c) {
                    const int p = r * 65 + 1 + (q << 2) + c;
                    u64 pk = (u64)f2bf(v0[c]) | ((u64)f2bf(v1[c]) << 16)
                           | ((u64)f2bf(v2[c]) << 32) | ((u64)f2bf(v3[c]) << 48);
                    *(u64*)&Xs[p * 72 + icg4 * 4] = pk;
                }
            }
        }
        __syncthreads();

        const short* wch = wg + (size_t)ch * 9 * 4096;
#pragma unroll
        for (int tap = 0; tap < 9; ++tap) {
            const int cur = tap & 1, nxt = cur ^ 1;
            if (tap < 8) {   // prefetch next tap's A-frags (overlaps MFMA below)
                const short* wn = wch + (tap + 1) * 4096;
#pragma unroll
                for (int f = 0; f < 8; ++f)
                    a[nxt][f] = *(const bf16x8*)&wn[f * 512 + lane * 8];
            }
            const int dy = tap / 3 - 1, dx = tap % 3 - 1;
#pragma unroll
            for (int kk = 0; kk < 2; ++kk) {
                bf16x8 b[8];
#pragma unroll
                for (int nn = 0; nn < 8; ++nn) {
                    const int j = (wc << 7) + (nn << 4) + l15;
                    const int p = ((j >> 6) + 1 + dy) * 65 + 1 + (j & 63) + dx;
                    b[nn] = *(const bf16x8*)&Xs[p * 72 + (kk * 4 + l4) * 8];
                }
#pragma unroll
                for (int m = 0; m < 4; ++m)
#pragma unroll
                    for (int nn = 0; nn < 8; ++nn)
                        acc[m][nn] = __builtin_amdgcn_mfma_f32_16x16x32_bf16(a[cur][kk * 4 + m], b[nn], acc[m][nn], 0, 0, 0);
            }
        }
    }

    // ---- epilogue: C/D layout col=lane&15 (pixel), row=(lane>>4)*4+r (oc) ----
#pragma unroll
    for (int m = 0; m < 4; ++m)
#pragma unroll
        for (int nn = 0; nn < 8; ++nn) {
            const int oc = (wr << 6) + (m << 4) + (l4 << 2);
            const int p  = (wc << 7) + (nn << 4) + l15;
            float* dst = outg + ((size_t)oc << 12) + p;
#pragma unroll
            for (int r = 0; r < 4; ++r) dst[(size_t)r << 12] = acc[m][nn][r];
        }
}

extern "C" void kernel_launch(void* const* d_in, const int* in_sizes, int n_in,
                              void* d_out, int out_size, void* d_ws, size_t ws_size,
                              hipStream_t stream) {
    const float* x      = (const float*)d_in[0];
    const float* style  = (const float*)d_in[1];
    const float* weight = (const float*)d_in[2];
    const float* demod  = (const float*)d_in[3];
    const float* mod_w  = (const float*)d_in[4];
    const float* mod_b  = (const float*)d_in[5];
    float* out = (float*)d_out;

    float* s_ws = (float*)d_ws;                         // 4*512 f32 = 8 KB
    short* wmod = (short*)((char*)d_ws + 8192);         // 4*9*512*512 bf16 = 18.9 MB

    hipLaunchKernelGGL(k_style, dim3(8), dim3(256), 0, stream, style, mod_w, mod_b, s_ws);
    hipLaunchKernelGGL(k_wmod, dim3(9216), dim3(256), 0, stream, weight, demod, s_ws, wmod);
    hipLaunchKernelGGL(k_conv, dim3(64, 4, 4), dim3(256), 0, stream, x, wmod, out);
}

// Round 3
// 421.702 us; speedup vs baseline: 1.4066x; 1.4066x over previous
//
#include <hip/hip_runtime.h>

typedef __attribute__((ext_vector_type(4))) float f32x4;
typedef __attribute__((ext_vector_type(8))) short bf16x8;
typedef unsigned long long u64;
typedef unsigned short u16;
typedef unsigned int u32;

// round-to-nearest-even f32 -> bf16 bits
static __device__ __forceinline__ u16 f2bf(float f) {
    u32 u = __float_as_uint(f);
    u += 0x7fffu + ((u >> 16) & 1u);
    return (u16)(u >> 16);
}

// ---------------- kernel 1: s[g][ic] = style[g] . mod_w[ic] + mod_b[ic] ----
__global__ void k_style(const float* __restrict__ style, const float* __restrict__ mod_w,
                        const float* __restrict__ mod_b, float* __restrict__ s_ws) {
    int t = blockIdx.x * 256 + threadIdx.x;     // 0..2047
    int g = t >> 9, ic = t & 511;
    const f32x4* st = (const f32x4*)(style + (g << 9));
    const f32x4* mw = (const f32x4*)(mod_w + (ic << 9));
    float acc = 0.f;
#pragma unroll 4
    for (int d = 0; d < 128; ++d) {
        f32x4 a = st[d], b = mw[d];
        acc += a[0]*b[0] + a[1]*b[1] + a[2]*b[2] + a[3]*b[3];
    }
    s_ws[t] = acc + mod_b[ic];
}

// ---------------- kernel 2: Wmod bf16, fragment-lane order ----------------
// Layout: [g(4)][ocb(4)][wr(2)][ch(8)][tap(9)][frag(8)][lane(64)][e(8)]
// frag = kk*4+m ; oc = ocb*128 + wr*64 + m*16 + l15 ; ic = ch*64+kk*32+l4*8+e
__global__ void k_wmod(const float* __restrict__ weight, const float* __restrict__ demod,
                       const float* __restrict__ s_ws, short* __restrict__ wmod) {
    int t = blockIdx.x * 256 + threadIdx.x;     // [0, 2359296)
    int lane = t & 63;
    int r = t >> 6;
    int frag = r & 7; r >>= 3;
    int tap = r % 9; r /= 9;
    int ch = r & 7; r >>= 3;
    int wr = r & 1; r >>= 1;
    int ocb = r & 3; int g = r >> 2;
    int kk = frag >> 2, m = frag & 3;
    int oc  = ocb*128 + wr*64 + m*16 + (lane & 15);
    int ic0 = ch*64 + kk*32 + (lane >> 4)*8;
    const float* wp = weight + (size_t)(oc*512 + ic0)*9 + tap;
    const float* sp = s_ws + (g << 9) + ic0;
    const float* dp = demod + ic0;
    bf16x8 pk;
#pragma unroll
    for (int e = 0; e < 8; ++e)
        pk[e] = (short)f2bf(wp[e*9] * (sp[e] * dp[e]));
    ((bf16x8*)wmod)[t] = pk;
}

// ---------------- kernel 3: main implicit-GEMM conv ------------------------
// Block: 128 oc x 256 px (4 rows), BK=64 ic, 4 waves (2 wr x 2 wc).
// W: global->register, static depth-1 pipeline (na0..na3 loop-carried named
// vars, no arrays with long live ranges -> no scratch). 2 barriers per chunk.
// Xs[391 slots][72 shorts]: slot p = row*65 + 1 + x; shared zero pad slots
// between rows. Stride 72 shorts (144 B) -> b128 reads land on 8 bank-quads
// x 8 lanes = throughput-optimal.
__global__ __launch_bounds__(256, 2) void k_conv(const float* __restrict__ x,
                                                 const short* __restrict__ wmod,
                                                 float* __restrict__ out) {
    __shared__ __align__(16) short Xs[391 * 72];   // 56304 B -> 2 blocks/CU

    const int tid  = threadIdx.x;
    const int lane = tid & 63;
    const int wv   = tid >> 6;
    const int wr   = wv >> 1, wc = wv & 1;
    const int l15  = lane & 15;
    const int l4   = lane >> 4;
    // XCD-locality: 4 ocb-siblings (same rowb, same x rows) are 16 apart in
    // blockIdx.x -> 16 % 8 == 0 -> same XCD -> x fetched once per XCD.
    const int rowb = blockIdx.x & 15, ocb = blockIdx.x >> 4;
    const int g    = blockIdx.y, nb = blockIdx.z;
    const int y0   = rowb << 2;

    const float* xg = x + (((size_t)(nb * 2048 + (g << 9))) << 12);
    const short* wg = wmod + ((size_t)((g * 4 + ocb) * 2 + wr)) * 294912;
    float* outg = out + (((size_t)(nb * 2048 + (g << 9) + ocb * 128)) << 12) + (rowb << 8);

    // per-lane W pointer; advances 2048 shorts (one kk-step = 4 frags) per step
    const short* wp   = wg + lane * 8;
    const short* wend = wg + 143 * 2048 + lane * 8;   // last step's base

    // prologue: prefetch step 0 (ch0,tap0,kk0)
    bf16x8 na0 = *(const bf16x8*)(wp);
    bf16x8 na1 = *(const bf16x8*)(wp + 512);
    bf16x8 na2 = *(const bf16x8*)(wp + 1024);
    bf16x8 na3 = *(const bf16x8*)(wp + 1536);
    wp += 2048;

    // zero Xs once (pad slots + out-of-image halo rows stay 0 forever)
    for (int i = tid; i < (391 * 72) / 4; i += 256) ((u64*)Xs)[i] = 0ull;

    f32x4 acc[4][8];
#pragma unroll
    for (int m = 0; m < 4; ++m)
#pragma unroll
        for (int nn = 0; nn < 8; ++nn) acc[m][nn] = (f32x4){0.f, 0.f, 0.f, 0.f};

    const int q = tid & 15, icg4 = tid >> 4;

#pragma unroll 1
    for (int ch = 0; ch < 8; ++ch) {
        __syncthreads();   // previous chunk's Xs reads complete

        // ---- stage X: fp32 -> bf16, transposed [slot p][ic] ----
#pragma unroll
        for (int r = 0; r < 6; ++r) {
            const int gy = y0 - 1 + r;
            if (gy >= 0 && gy <= 63) {
                const float* src = xg + (((size_t)((ch << 6) + (icg4 << 2))) << 12) + (gy << 6) + (q << 2);
                f32x4 v0 = *(const f32x4*)(src);
                f32x4 v1 = *(const f32x4*)(src + 4096);
                f32x4 v2 = *(const f32x4*)(src + 8192);
                f32x4 v3 = *(const f32x4*)(src + 12288);
#pragma unroll
                for (int c = 0; c < 4; ++c) {
                    const int p = r * 65 + 1 + (q << 2) + c;
                    u64 pk = (u64)f2bf(v0[c]) | ((u64)f2bf(v1[c]) << 16)
                           | ((u64)f2bf(v2[c]) << 32) | ((u64)f2bf(v3[c]) << 48);
                    *(u64*)&Xs[p * 72 + icg4 * 4] = pk;
                }
            }
        }
        __syncthreads();

#pragma unroll
        for (int tap = 0; tap < 9; ++tap) {
            const int dy = tap / 3 - 1, dx = tap % 3 - 1;
#pragma unroll
            for (int kk = 0; kk < 2; ++kk) {
                // consume prefetched step, issue next (static names -> no scratch)
                bf16x8 ca0 = na0, ca1 = na1, ca2 = na2, ca3 = na3;
                na0 = *(const bf16x8*)(wp);
                na1 = *(const bf16x8*)(wp + 512);
                na2 = *(const bf16x8*)(wp + 1024);
                na3 = *(const bf16x8*)(wp + 1536);
                wp = (wp < wend) ? (wp + 2048) : wp;   // clamp at final step

                bf16x8 b[8];
#pragma unroll
                for (int nn = 0; nn < 8; ++nn) {
                    const int j = (wc << 7) + (nn << 4) + l15;
                    const int p = ((j >> 6) + 1 + dy) * 65 + 1 + (j & 63) + dx;
                    b[nn] = *(const bf16x8*)&Xs[p * 72 + (kk * 4 + l4) * 8];
                }
#pragma unroll
                for (int nn = 0; nn < 8; ++nn) {
                    acc[0][nn] = __builtin_amdgcn_mfma_f32_16x16x32_bf16(ca0, b[nn], acc[0][nn], 0, 0, 0);
                    acc[1][nn] = __builtin_amdgcn_mfma_f32_16x16x32_bf16(ca1, b[nn], acc[1][nn], 0, 0, 0);
                    acc[2][nn] = __builtin_amdgcn_mfma_f32_16x16x32_bf16(ca2, b[nn], acc[2][nn], 0, 0, 0);
                    acc[3][nn] = __builtin_amdgcn_mfma_f32_16x16x32_bf16(ca3, b[nn], acc[3][nn], 0, 0, 0);
                }
            }
        }
    }

    // ---- epilogue: C/D layout col=lane&15 (pixel), row=(lane>>4)*4+r (oc) ----
#pragma unroll
    for (int m = 0; m < 4; ++m)
#pragma unroll
        for (int nn = 0; nn < 8; ++nn) {
            const int oc = (wr << 6) + (m << 4) + (l4 << 2);
            const int p  = (wc << 7) + (nn << 4) + l15;
            float* dst = outg + ((size_t)oc << 12) + p;
#pragma unroll
            for (int r = 0; r < 4; ++r) dst[(size_t)r << 12] = acc[m][nn][r];
        }
}

extern "C" void kernel_launch(void* const* d_in, const int* in_sizes, int n_in,
                              void* d_out, int out_size, void* d_ws, size_t ws_size,
                              hipStream_t stream) {
    const float* x      = (const float*)d_in[0];
    const float* style  = (const float*)d_in[1];
    const float* weight = (const float*)d_in[2];
    const float* demod  = (const float*)d_in[3];
    const float* mod_w  = (const float*)d_in[4];
    const float* mod_b  = (const float*)d_in[5];
    float* out = (float*)d_out;

    float* s_ws = (float*)d_ws;                         // 4*512 f32 = 8 KB
    short* wmod = (short*)((char*)d_ws + 8192);         // 4*9*512*512 bf16 = 18.9 MB

    hipLaunchKernelGGL(k_style, dim3(8), dim3(256), 0, stream, style, mod_w, mod_b, s_ws);
    hipLaunchKernelGGL(k_wmod, dim3(9216), dim3(256), 0, stream, weight, demod, s_ws, wmod);
    hipLaunchKernelGGL(k_conv, dim3(64, 4, 4), dim3(256), 0, stream, x, wmod, out);
}